// Round 13
// baseline (184.508 us; speedup 1.0000x reference)
//
#include <hip/hip_runtime.h>
#include <math.h>

// ---------------------------------------------------------------------------
// Barrier_Net, full-f16 MFMA (16x16x32). One wave = 16 batch rows end-to-end.
// R13 vs R12:
//  - x rows (5440 B contiguous) staged into LDS once via coalesced dwordx4 +
//    ds_write_b128 -> all x accesses become pipelined LDS broadcasts
//  - neighbor & obstacle chains interleaved in the same fence segments with
//    separate LDS areas -> 6 order points (was 10), 2 indep MFMA streams each
//  - soft fences (R11-proven), rows-on-M stage-1 (R12), block 256.
// A-frag: A[m=lane&15][k=(lane>>4)*8+j]; B-frag: B[k=(lane>>4)*8+j][n=lane&15]
// C/D: col=lane&15, row=(lane>>4)*4+reg.  (HW-verified R7..R12)
// ---------------------------------------------------------------------------

typedef __attribute__((ext_vector_type(8))) _Float16 f16x8;
typedef __attribute__((ext_vector_type(2))) __fp16 fp16x2;
typedef __attribute__((ext_vector_type(4))) float f32x4;

#define XW 85     // floats per input row
#define WPB 4     // waves per block

// ---- B-frag table in d_ws: 34 frags x 64 lanes x 8 f16 ----
#define FR_S1N  0
#define FR_S1O  4
#define FR_G2N  8
#define FR_G2O  10
#define FR_RNA  12
#define FR_RNB  16
#define FR_ROA  18
#define FR_ROB  22
#define FR_PSI1 24
#define FR_PSI2 32
#define N_FRAGS 34

// ---- per-wave LDS layout (bytes) ----
#define X_STR   340     // one x row, fp32
#define BIG_STR 144
#define PHI_STR 80
#define CAT_STR 144
#define L_XBUF 0        // 16 x 340 = 5440 (pad to 5504)
#define L_BIGN 5504     // 2304
#define L_BIGO 7808     // 2304
#define L_PHN  10112    // 1280
#define L_PHO  11392    // 1280
#define L_CAT  12672    // 2304
#define L_OUT  14976    // 128
#define L_BAR  15104    // 128
#define WAVE_LDS 15360  // x4 waves = 61440 B/block

__device__ __forceinline__ float fast_rcp(float x)  { return __builtin_amdgcn_rcpf(x); }
__device__ __forceinline__ float fast_sqrt(float x) { return __builtin_amdgcn_sqrtf(x); }

__device__ __forceinline__ float two_tanh(float a) {
    float ax = fabsf(a);
    float e = __expf(2.0f * ax);
    float t = 1.0f - 2.0f * fast_rcp(e + 1.0f);
    return copysignf(2.0f * t, a);
}

// Compiler-only ordering barrier (R11-proven: per-wave DS ordering suffices
// for wave-private LDS).
__device__ __forceinline__ void lds_order() {
    __asm__ __volatile__("" ::: "memory");
}

__device__ __forceinline__ unsigned pk2(float a, float b) {
    union { fp16x2 h; unsigned u; } t;
    t.h = __builtin_amdgcn_cvt_pkrtz(a, b);
    return t.u;
}
__device__ __forceinline__ f16x8 make_a4(float f0, float f1, float f2, float f3) {
    union { unsigned u[4]; f16x8 v; } U;
    U.u[0] = pk2(f0, f1); U.u[1] = pk2(f2, f3); U.u[2] = 0; U.u[3] = 0;
    return U.v;
}
__device__ __forceinline__ f16x8 make_a2(float f0, float f1) {
    union { unsigned u[4]; f16x8 v; } U;
    U.u[0] = pk2(f0, f1); U.u[1] = 0; U.u[2] = 0; U.u[3] = 0;
    return U.v;
}
__device__ __forceinline__ f16x8 lds_af(const char* area, int stride, int off, int lane) {
    int mm = lane & 15, qq = lane >> 4;
    return *(const f16x8*)(area + mm * stride + off + qq * 16);
}
__device__ __forceinline__ f16x8 load_bh(const _Float16* wsf, int frag, int lane) {
    return ((const f16x8*)(wsf + (size_t)frag * 512))[lane];
}
__device__ __forceinline__ f32x4 cinit(float b) {
    f32x4 c; c[0] = b; c[1] = b; c[2] = b; c[3] = b; return c;
}
__device__ __forceinline__ f32x4 mfma1(f16x8 a, f16x8 b, f32x4 c) {
    return __builtin_amdgcn_mfma_f32_16x16x32_f16(a, b, c, 0, 0, 0);
}

// ---------------------------------------------------------------------------
// prep: pack weights into f16 B-frag blocks, zero outside (K,N). (unchanged)
// ---------------------------------------------------------------------------
__global__ void bn_prep(const float* __restrict__ Wp1n, const float* __restrict__ Wp2n,
                        const float* __restrict__ Wr1n, const float* __restrict__ Wr2n,
                        const float* __restrict__ Wp1o, const float* __restrict__ Wp2o,
                        const float* __restrict__ Wr1o, const float* __restrict__ Wr2o,
                        const float* __restrict__ Wpsi1, const float* __restrict__ Wpsi2,
                        _Float16* __restrict__ wsf)
{
    int f = blockIdx.x;
    int lane = threadIdx.x;   // 64
    const float* W; int K, N, kk = 0, nt = 0, rel;
    if (f < 4)        { W = Wp1n;  K = 4;  N = 64; nt = f; }
    else if (f < 8)   { W = Wp1o;  K = 2;  N = 64; nt = f - 4; }
    else if (f < 10)  { W = Wp2n;  K = 64; N = 16; kk = f - 8; }
    else if (f < 12)  { W = Wp2o;  K = 64; N = 16; kk = f - 10; }
    else if (f < 16)  { W = Wr1n;  K = 16; N = 64; nt = f - 12; }
    else if (f < 18)  { W = Wr2n;  K = 64; N = 16; kk = f - 16; }
    else if (f < 22)  { W = Wr1o;  K = 16; N = 64; nt = f - 18; }
    else if (f < 24)  { W = Wr2o;  K = 64; N = 16; kk = f - 22; }
    else if (f < 32)  { rel = f - 24; W = Wpsi1; K = 36; N = 64; kk = rel >> 2; nt = rel & 3; }
    else              { W = Wpsi2; K = 64; N = 2;  kk = f - 32; }

    int q = lane >> 4, c = lane & 15;
    _Float16* dst = wsf + (size_t)f * 512 + lane * 8;
    for (int j = 0; j < 8; ++j) {
        int k = kk * 32 + q * 8 + j;
        int n = nt * 16 + c;
        float v = (k < K && n < N) ? W[k * N + n] : 0.f;
        dst[j] = (_Float16)v;
    }
}

// ---------------------------------------------------------------------------
// main: 1 wave = 16 rows; block 256 = 4 waves.
// ---------------------------------------------------------------------------
__global__ __launch_bounds__(256) void bn_main(
    const float* __restrict__ x, const _Float16* __restrict__ wsf,
    const float* __restrict__ bp1n, const float* __restrict__ bp2n,
    const float* __restrict__ br1n, const float* __restrict__ br2n,
    const float* __restrict__ bp1o, const float* __restrict__ bp2o,
    const float* __restrict__ br1o, const float* __restrict__ br2o,
    const float* __restrict__ bpsi1, const float* __restrict__ bpsi2,
    float* __restrict__ out, int nb)
{
    __shared__ char smem[WPB * WAVE_LDS];
    const int lane = threadIdx.x & 63;
    const int wid  = threadIdx.x >> 6;
    const int group = blockIdx.x * WPB + wid;
    const int row0 = group * 16;
    if (row0 >= nb) return;

    char* Wl   = smem + wid * WAVE_LDS;
    char* XB   = Wl + L_XBUF;
    char* BIGN = Wl + L_BIGN;
    char* BIGO = Wl + L_BIGO;
    char* PHN  = Wl + L_PHN;
    char* PHO  = Wl + L_PHO;
    char* CAT  = Wl + L_CAT;
    char* OUTA = Wl + L_OUT;
    char* BAR  = Wl + L_BAR;

    const int m = lane & 15, q = lane >> 4, c = m;

    // ---- stage this group's 16 x rows into LDS (coalesced, one shot) ------
    // rows are contiguous: bytes [row0*340, row0*340 + 5440); base 16B-aligned
    {
        const uint4* xb = (const uint4*)(x + (size_t)row0 * XW);   // 340 uint4
        uint4 t[6];
        #pragma unroll
        for (int cch = 0; cch < 6; ++cch) {
            int idx = cch * 64 + lane;
            if (idx < 340) t[cch] = xb[idx];
        }
        #pragma unroll
        for (int cch = 0; cch < 6; ++cch) {
            int idx = cch * 64 + lane;
            if (idx < 340) *(uint4*)(XB + idx * 16) = t[cch];
        }
    }

    // zero junk zones: PHN/PHO bytes 32..63, CAT bytes 64..127 (per row)
    for (int i = lane; i < 128; i += 64) {
        int r = i >> 3, d = i & 7;
        *(unsigned*)(PHN + r * PHI_STR + 32 + d * 4) = 0;
        *(unsigned*)(PHO + r * PHI_STR + 32 + d * 4) = 0;
    }
    for (int i = lane; i < 256; i += 64) {
        int r = i >> 4, d = i & 15;
        *(unsigned*)(CAT + r * CAT_STR + 64 + d * 4) = 0;
    }
    lds_order();

    // biases (per output column c) — scalar loads, overlap with staging
    float b_s1n[4], b_s1o[4], b_rna[4], b_roa[4], b_p1[4];
    #pragma unroll
    for (int nt = 0; nt < 4; ++nt) {
        b_s1n[nt] = bp1n[nt * 16 + c];
        b_s1o[nt] = bp1o[nt * 16 + c];
        b_rna[nt] = br1n[nt * 16 + c];
        b_roa[nt] = br1o[nt * 16 + c];
        b_p1[nt]  = bpsi1[nt * 16 + c];
    }
    float b_g2n = 16.f * bp2n[c];
    float b_g2o = 8.f * bp2o[c];
    float b_rnb = br2n[c];
    float b_rob = br2o[c];
    float b_p2  = (c < 2) ? bpsi2[c] : 0.f;

    // stage-A/B B-frags
    f16x8 Bs1n[4], Bs1o[4], Bg2n[2], Bg2o[2];
    #pragma unroll
    for (int nt = 0; nt < 4; ++nt) Bs1n[nt] = load_bh(wsf, FR_S1N + nt, lane);
    #pragma unroll
    for (int nt = 0; nt < 4; ++nt) Bs1o[nt] = load_bh(wsf, FR_S1O + nt, lane);
    Bg2n[0] = load_bh(wsf, FR_G2N + 0, lane);
    Bg2n[1] = load_bh(wsf, FR_G2N + 1, lane);
    Bg2o[0] = load_bh(wsf, FR_G2O + 0, lane);
    Bg2o[1] = load_bh(wsf, FR_G2O + 1, lane);

    const float* XR = (const float*)(XB + m * X_STR);   // this lane's row

    // ---- barrier terms (reads from LDS): lane (row=m, quad q) handles
    //      nbrs 4q..4q+3 and obstacles 2q..2q+1; 4 shuffles total ----
    {
        float bx = 0.f, by = 0.f;
        #pragma unroll
        for (int i = 0; i < 4; ++i) {
            int n = 4 * q + i;
            float px = -XR[5 + 4 * n], py = -XR[6 + 4 * n];
            float nrm = fast_sqrt(px * px + py * py);
            float coef = 0.05f * fast_rcp(nrm * (nrm - 0.3f));
            bx = fmaf(coef, px, bx);
            by = fmaf(coef, py, by);
        }
        #pragma unroll
        for (int i = 0; i < 2; ++i) {
            int o = 2 * q + i;
            float px = -XR[69 + 2 * o], py = -XR[70 + 2 * o];
            float nrm = fast_sqrt(px * px + py * py);
            float coef = 0.05f * fast_rcp(nrm * (nrm - 0.3f));
            bx = fmaf(coef, px, bx);
            by = fmaf(coef, py, by);
        }
        bx += __shfl_xor(bx, 16); by += __shfl_xor(by, 16);
        bx += __shfl_xor(bx, 32); by += __shfl_xor(by, 32);
        if (q == 0) { float2 bb; bb.x = bx; bb.y = by; *(float2*)(BAR + m * 8) = bb; }
    }

    // g -> CAT k=32..35 (bytes 64..71)
    if (lane < 16) {
        const float* xr = (const float*)(XB + lane * X_STR);
        uint2 gv;
        gv.x = pk2(xr[1], xr[2]);
        gv.y = pk2(xr[3], xr[4]);
        *(uint2*)(CAT + lane * CAT_STR + 64) = gv;
    }

    // ======== STAGE A: S1N + S1O (rows-on-M, register accumulation) ========
    {
        f32x4 accN[4], accO[4];
        #pragma unroll
        for (int nt = 0; nt < 4; ++nt) { accN[nt] = cinit(0.f); accO[nt] = cinit(0.f); }

        #pragma unroll
        for (int oo = 0; oo < 8; ++oo) {
            f16x8 A = make_a2(XR[69 + 2 * oo], XR[70 + 2 * oo]);
            #pragma unroll
            for (int nt = 0; nt < 4; ++nt) {
                f32x4 cc = mfma1(A, Bs1o[nt], cinit(b_s1o[nt]));
                #pragma unroll
                for (int reg = 0; reg < 4; ++reg)
                    accO[nt][reg] += fmaxf(cc[reg], 0.f);
            }
        }
        #pragma unroll 8
        for (int mm = 0; mm < 16; ++mm) {
            const float* e = XR + 5 + 4 * mm;
            f16x8 A = make_a4(e[0], e[1], e[2], e[3]);
            #pragma unroll
            for (int nt = 0; nt < 4; ++nt) {
                f32x4 cc = mfma1(A, Bs1n[nt], cinit(b_s1n[nt]));
                #pragma unroll
                for (int reg = 0; reg < 4; ++reg)
                    accN[nt][reg] += fmaxf(cc[reg], 0.f);
            }
        }
        #pragma unroll
        for (int nt = 0; nt < 4; ++nt)
            #pragma unroll
            for (int reg = 0; reg < 4; ++reg) {
                *(_Float16*)(BIGN + (q * 4 + reg) * BIG_STR + (nt * 16 + c) * 2) = (_Float16)accN[nt][reg];
                *(_Float16*)(BIGO + (q * 4 + reg) * BIG_STR + (nt * 16 + c) * 2) = (_Float16)accO[nt][reg];
            }
    }
    f16x8 Brna[4], Broa[4];
    #pragma unroll
    for (int nt = 0; nt < 4; ++nt) Brna[nt] = load_bh(wsf, FR_RNA + nt, lane);
    #pragma unroll
    for (int nt = 0; nt < 4; ++nt) Broa[nt] = load_bh(wsf, FR_ROA + nt, lane);
    lds_order();

    // ======== STAGE B: G2N + G2O -> PHN / PHO ==============================
    {
        f16x8 An0 = lds_af(BIGN, BIG_STR, 0, lane);
        f16x8 An1 = lds_af(BIGN, BIG_STR, 64, lane);
        f16x8 Ao0 = lds_af(BIGO, BIG_STR, 0, lane);
        f16x8 Ao1 = lds_af(BIGO, BIG_STR, 64, lane);
        f32x4 cn = mfma1(An0, Bg2n[0], cinit(b_g2n));
        f32x4 co = mfma1(Ao0, Bg2o[0], cinit(b_g2o));
        f32x4 cn1 = mfma1(An1, Bg2n[1], cinit(0.f));
        f32x4 co1 = mfma1(Ao1, Bg2o[1], cinit(0.f));
        #pragma unroll
        for (int reg = 0; reg < 4; ++reg) {
            *(_Float16*)(PHN + (q * 4 + reg) * PHI_STR + c * 2) = (_Float16)(cn[reg] + cn1[reg]);
            *(_Float16*)(PHO + (q * 4 + reg) * PHI_STR + c * 2) = (_Float16)(co[reg] + co1[reg]);
        }
    }
    f16x8 Brnb[2], Brob[2];
    Brnb[0] = load_bh(wsf, FR_RNB + 0, lane);
    Brnb[1] = load_bh(wsf, FR_RNB + 1, lane);
    Brob[0] = load_bh(wsf, FR_ROB + 0, lane);
    Brob[1] = load_bh(wsf, FR_ROB + 1, lane);
    lds_order();

    // ======== STAGE C: RNA + ROA -> BIGN / BIGO ============================
    {
        f16x8 An = lds_af(PHN, PHI_STR, 0, lane);   // k>=16 zero-filled
        f16x8 Ao = lds_af(PHO, PHI_STR, 0, lane);
        #pragma unroll
        for (int nt = 0; nt < 4; ++nt) {
            f32x4 cn = mfma1(An, Brna[nt], cinit(b_rna[nt]));
            f32x4 co = mfma1(Ao, Broa[nt], cinit(b_roa[nt]));
            #pragma unroll
            for (int reg = 0; reg < 4; ++reg) {
                *(_Float16*)(BIGN + (q * 4 + reg) * BIG_STR + (nt * 16 + c) * 2) = (_Float16)fmaxf(cn[reg], 0.f);
                *(_Float16*)(BIGO + (q * 4 + reg) * BIG_STR + (nt * 16 + c) * 2) = (_Float16)fmaxf(co[reg], 0.f);
            }
        }
    }
    f16x8 Bp1a[4], Bp1b[4];
    #pragma unroll
    for (int nt = 0; nt < 4; ++nt) Bp1a[nt] = load_bh(wsf, FR_PSI1 + nt, lane);
    #pragma unroll
    for (int nt = 0; nt < 4; ++nt) Bp1b[nt] = load_bh(wsf, FR_PSI1 + 4 + nt, lane);
    lds_order();

    // ======== STAGE D: RNB + ROB -> CAT (cols 0..15 / 16..31) ==============
    {
        f16x8 An0 = lds_af(BIGN, BIG_STR, 0, lane);
        f16x8 An1 = lds_af(BIGN, BIG_STR, 64, lane);
        f16x8 Ao0 = lds_af(BIGO, BIG_STR, 0, lane);
        f16x8 Ao1 = lds_af(BIGO, BIG_STR, 64, lane);
        f32x4 cn = mfma1(An0, Brnb[0], cinit(b_rnb));
        f32x4 co = mfma1(Ao0, Brob[0], cinit(b_rob));
        f32x4 cn1 = mfma1(An1, Brnb[1], cinit(0.f));
        f32x4 co1 = mfma1(Ao1, Brob[1], cinit(0.f));
        #pragma unroll
        for (int reg = 0; reg < 4; ++reg) {
            *(_Float16*)(CAT + (q * 4 + reg) * CAT_STR + c * 2)        = (_Float16)(cn[reg] + cn1[reg]);
            *(_Float16*)(CAT + (q * 4 + reg) * CAT_STR + (16 + c) * 2) = (_Float16)(co[reg] + co1[reg]);
        }
    }
    f16x8 Bp2[2];
    Bp2[0] = load_bh(wsf, FR_PSI2 + 0, lane);
    Bp2[1] = load_bh(wsf, FR_PSI2 + 1, lane);
    lds_order();

    // ======== STAGE E: PSI1 -> BIGN ========================================
    {
        f16x8 A0 = lds_af(CAT, CAT_STR, 0, lane);    // k 0..31
        f16x8 A1 = lds_af(CAT, CAT_STR, 64, lane);   // k 32..63 (36.. zero)
        #pragma unroll
        for (int nt = 0; nt < 4; ++nt) {
            f32x4 ca = mfma1(A0, Bp1a[nt], cinit(b_p1[nt]));
            f32x4 cb = mfma1(A1, Bp1b[nt], cinit(0.f));
            #pragma unroll
            for (int reg = 0; reg < 4; ++reg)
                *(_Float16*)(BIGN + (q * 4 + reg) * BIG_STR + (nt * 16 + c) * 2) = (_Float16)fmaxf(ca[reg] + cb[reg], 0.f);
        }
    }
    lds_order();

    // ======== STAGE F: PSI2 -> a0,a1; epilogue =============================
    {
        f16x8 A0 = lds_af(BIGN, BIG_STR, 0, lane);
        f16x8 A1 = lds_af(BIGN, BIG_STR, 64, lane);
        f32x4 ca = mfma1(A0, Bp2[0], cinit(b_p2));
        f32x4 cb = mfma1(A1, Bp2[1], cinit(0.f));
        if (c < 2) {
            #pragma unroll
            for (int reg = 0; reg < 4; ++reg)
                *(float*)(OUTA + (q * 4 + reg) * 8 + c * 4) = ca[reg] + cb[reg];
        }
    }
    lds_order();

    if (lane < 16) {
        float2 a  = *(const float2*)(OUTA + lane * 8);
        float2 bb = *(const float2*)(BAR + lane * 8);
        float a0 = two_tanh(a.x) + bb.x;
        float a1 = two_tanh(a.y) + bb.y;
        float amax = fmaxf(fabsf(a0), fabsf(a1));
        float inv_alpha = fmaxf(amax * 0.5f, 1.0f);
        float rr = fast_rcp(inv_alpha);
        float2 o; o.x = a0 * rr; o.y = a1 * rr;
        *(float2*)(out + (size_t)(row0 + lane) * 2) = o;
    }
}

extern "C" void kernel_launch(void* const* d_in, const int* in_sizes, int n_in,
                              void* d_out, int out_size, void* d_ws, size_t ws_size,
                              hipStream_t stream) {
    const float* x     = (const float*)d_in[0];
    const float* Wp1n  = (const float*)d_in[1];
    const float* bp1n  = (const float*)d_in[2];
    const float* Wp2n  = (const float*)d_in[3];
    const float* bp2n  = (const float*)d_in[4];
    const float* Wr1n  = (const float*)d_in[5];
    const float* br1n  = (const float*)d_in[6];
    const float* Wr2n  = (const float*)d_in[7];
    const float* br2n  = (const float*)d_in[8];
    const float* Wp1o  = (const float*)d_in[9];
    const float* bp1o  = (const float*)d_in[10];
    const float* Wp2o  = (const float*)d_in[11];
    const float* bp2o  = (const float*)d_in[12];
    const float* Wr1o  = (const float*)d_in[13];
    const float* br1o  = (const float*)d_in[14];
    const float* Wr2o  = (const float*)d_in[15];
    const float* br2o  = (const float*)d_in[16];
    const float* Wpsi1 = (const float*)d_in[17];
    const float* bpsi1 = (const float*)d_in[18];
    const float* Wpsi2 = (const float*)d_in[19];
    const float* bpsi2 = (const float*)d_in[20];
    float* out = (float*)d_out;

    int nb = in_sizes[0] / XW;               // 131072
    _Float16* wsf = (_Float16*)d_ws;         // ~34 KB frag table

    bn_prep<<<N_FRAGS, 64, 0, stream>>>(Wp1n, Wp2n, Wr1n, Wr2n,
                                        Wp1o, Wp2o, Wr1o, Wr2o,
                                        Wpsi1, Wpsi2, wsf);

    int groups = (nb + 15) / 16;             // 8192
    int blocks = (groups + WPB - 1) / WPB;   // 2048
    bn_main<<<blocks, 256, 0, stream>>>(x, wsf,
                                        bp1n, bp2n, br1n, br2n,
                                        bp1o, bp2o, br1o, br2o,
                                        bpsi1, bpsi2, out, nb);
}

// Round 14
// 151.164 us; speedup vs baseline: 1.2206x; 1.2206x over previous
//
#include <hip/hip_runtime.h>
#include <math.h>

// ---------------------------------------------------------------------------
// Barrier_Net, full-f16 MFMA (16x16x32), WAVE-SPLIT pipeline.
// Group = 16 batch rows handled by a PAIR of waves:
//   wave0: S1N -> G2N -> RNA -> RNB -> CAT cols 0..15      (neighbor chain)
//   wave1: barrier+g, S1O -> G2O -> ROA -> ROB -> CAT 16..31 (obstacle chain)
//   __syncthreads (CAT handoff), then wave1: PSI1 -> PSI2 -> epilogue.
// Halves per-wave serial chain; doubles wave count (16384, 4+/SIMD).
// A-frag: A[m=lane&15][k=(lane>>4)*8+j]; B-frag: B[k=(lane>>4)*8+j][n=lane&15]
// C/D: col=lane&15, row=(lane>>4)*4+reg.  (HW-verified R7..R12)
// Wave-private LDS uses soft fences (R11-proven); cross-wave CAT uses the
// hardware barrier. nb = 131072 = 16*8192 rows -> 4096 full blocks, no
// partial groups (barrier safe).
// ---------------------------------------------------------------------------

typedef __attribute__((ext_vector_type(8))) _Float16 f16x8;
typedef __attribute__((ext_vector_type(2))) __fp16 fp16x2;
typedef __attribute__((ext_vector_type(4))) float f32x4;

#define XW 85     // floats per input row

// ---- B-frag table in d_ws: 34 frags x 64 lanes x 8 f16 ----
#define FR_S1N  0
#define FR_S1O  4
#define FR_G2N  8
#define FR_G2O  10
#define FR_RNA  12
#define FR_RNB  16
#define FR_ROA  18
#define FR_ROB  22
#define FR_PSI1 24
#define FR_PSI2 32
#define N_FRAGS 34

// ---- per-GROUP LDS layout (bytes); 2 groups per 256-thread block ----
#define BIG_STR 144
#define PHI_STR 80
#define CAT_STR 144
#define L_BIGN 0        // 2304  (wave0 private)
#define L_BIGO 2304     // 2304  (wave1 private; reused for h3)
#define L_PHN  4608     // 1280  (wave0 private)
#define L_PHO  5888     // 1280  (wave1 private)
#define L_CAT  7168     // 2304  (cross-wave, barrier-protected)
#define L_OUT  9472     // 128
#define L_BAR  9600     // 128
#define GRP_LDS 9728    // x2 groups = 19456 B/block -> wave-limited 8 blk/CU

__device__ __forceinline__ float fast_rcp(float x)  { return __builtin_amdgcn_rcpf(x); }
__device__ __forceinline__ float fast_sqrt(float x) { return __builtin_amdgcn_sqrtf(x); }

__device__ __forceinline__ float two_tanh(float a) {
    float ax = fabsf(a);
    float e = __expf(2.0f * ax);
    float t = 1.0f - 2.0f * fast_rcp(e + 1.0f);
    return copysignf(2.0f * t, a);
}

// Compiler-only ordering barrier for wave-private LDS (R11-proven safe).
__device__ __forceinline__ void lds_order() {
    __asm__ __volatile__("" ::: "memory");
}

__device__ __forceinline__ unsigned pk2(float a, float b) {
    union { fp16x2 h; unsigned u; } t;
    t.h = __builtin_amdgcn_cvt_pkrtz(a, b);
    return t.u;
}
__device__ __forceinline__ f16x8 make_a4(float f0, float f1, float f2, float f3) {
    union { unsigned u[4]; f16x8 v; } U;
    U.u[0] = pk2(f0, f1); U.u[1] = pk2(f2, f3); U.u[2] = 0; U.u[3] = 0;
    return U.v;
}
__device__ __forceinline__ f16x8 make_a2(float f0, float f1) {
    union { unsigned u[4]; f16x8 v; } U;
    U.u[0] = pk2(f0, f1); U.u[1] = 0; U.u[2] = 0; U.u[3] = 0;
    return U.v;
}
__device__ __forceinline__ f16x8 lds_af(const char* area, int stride, int off, int lane) {
    int mm = lane & 15, qq = lane >> 4;
    return *(const f16x8*)(area + mm * stride + off + qq * 16);
}
__device__ __forceinline__ f16x8 load_bh(const _Float16* wsf, int frag, int lane) {
    return ((const f16x8*)(wsf + (size_t)frag * 512))[lane];
}
__device__ __forceinline__ f32x4 cinit(float b) {
    f32x4 c; c[0] = b; c[1] = b; c[2] = b; c[3] = b; return c;
}
__device__ __forceinline__ f32x4 mfma1(f16x8 a, f16x8 b, f32x4 c) {
    return __builtin_amdgcn_mfma_f32_16x16x32_f16(a, b, c, 0, 0, 0);
}

// ---------------------------------------------------------------------------
// prep: pack weights into f16 B-frag blocks, zero outside (K,N). (unchanged)
// ---------------------------------------------------------------------------
__global__ void bn_prep(const float* __restrict__ Wp1n, const float* __restrict__ Wp2n,
                        const float* __restrict__ Wr1n, const float* __restrict__ Wr2n,
                        const float* __restrict__ Wp1o, const float* __restrict__ Wp2o,
                        const float* __restrict__ Wr1o, const float* __restrict__ Wr2o,
                        const float* __restrict__ Wpsi1, const float* __restrict__ Wpsi2,
                        _Float16* __restrict__ wsf)
{
    int f = blockIdx.x;
    int lane = threadIdx.x;   // 64
    const float* W; int K, N, kk = 0, nt = 0, rel;
    if (f < 4)        { W = Wp1n;  K = 4;  N = 64; nt = f; }
    else if (f < 8)   { W = Wp1o;  K = 2;  N = 64; nt = f - 4; }
    else if (f < 10)  { W = Wp2n;  K = 64; N = 16; kk = f - 8; }
    else if (f < 12)  { W = Wp2o;  K = 64; N = 16; kk = f - 10; }
    else if (f < 16)  { W = Wr1n;  K = 16; N = 64; nt = f - 12; }
    else if (f < 18)  { W = Wr2n;  K = 64; N = 16; kk = f - 16; }
    else if (f < 22)  { W = Wr1o;  K = 16; N = 64; nt = f - 18; }
    else if (f < 24)  { W = Wr2o;  K = 64; N = 16; kk = f - 22; }
    else if (f < 32)  { rel = f - 24; W = Wpsi1; K = 36; N = 64; kk = rel >> 2; nt = rel & 3; }
    else              { W = Wpsi2; K = 64; N = 2;  kk = f - 32; }

    int q = lane >> 4, c = lane & 15;
    _Float16* dst = wsf + (size_t)f * 512 + lane * 8;
    for (int j = 0; j < 8; ++j) {
        int k = kk * 32 + q * 8 + j;
        int n = nt * 16 + c;
        float v = (k < K && n < N) ? W[k * N + n] : 0.f;
        dst[j] = (_Float16)v;
    }
}

// ---------------------------------------------------------------------------
// main: 2 waves per 16-row group; block 256 = 4 waves = 2 groups.
// ---------------------------------------------------------------------------
__global__ __launch_bounds__(256) void bn_main(
    const float* __restrict__ x, const _Float16* __restrict__ wsf,
    const float* __restrict__ bp1n, const float* __restrict__ bp2n,
    const float* __restrict__ br1n, const float* __restrict__ br2n,
    const float* __restrict__ bp1o, const float* __restrict__ bp2o,
    const float* __restrict__ br1o, const float* __restrict__ br2o,
    const float* __restrict__ bpsi1, const float* __restrict__ bpsi2,
    float* __restrict__ out, int nb)
{
    __shared__ char smem[2 * GRP_LDS];
    const int lane = threadIdx.x & 63;
    const int wid  = threadIdx.x >> 6;
    const int grp  = wid >> 1;          // group within block (0..1)
    const int role = wid & 1;           // 0 = neighbor chain, 1 = obstacle+psi
    const int group = blockIdx.x * 2 + grp;
    const int row0 = group * 16;        // nb is an exact multiple of 16*2

    char* Gl   = smem + grp * GRP_LDS;
    char* BIGN = Gl + L_BIGN;
    char* BIGO = Gl + L_BIGO;
    char* PHN  = Gl + L_PHN;
    char* PHO  = Gl + L_PHO;
    char* CAT  = Gl + L_CAT;
    char* OUTA = Gl + L_OUT;
    char* BAR  = Gl + L_BAR;

    const int m = lane & 15, q = lane >> 4, c = m;
    const float* xrow = x + (size_t)(row0 + m) * XW;   // this lane's batch row

    if (role == 0) {
        // =================== WAVE 0: neighbor chain =========================
        // zero PHN junk (bytes 32..63 per row)
        for (int i = lane; i < 128; i += 64) {
            int r = i >> 3, d = i & 7;
            *(unsigned*)(PHN + r * PHI_STR + 32 + d * 4) = 0;
        }
        lds_order();

        float b_s1n[4], b_rna[4];
        #pragma unroll
        for (int nt = 0; nt < 4; ++nt) {
            b_s1n[nt] = bp1n[nt * 16 + c];
            b_rna[nt] = br1n[nt * 16 + c];
        }
        float b_g2n = 16.f * bp2n[c];
        float b_rnb = br2n[c];

        f16x8 Bs1n[4], Bg2n[2];
        #pragma unroll
        for (int nt = 0; nt < 4; ++nt) Bs1n[nt] = load_bh(wsf, FR_S1N + nt, lane);
        Bg2n[0] = load_bh(wsf, FR_G2N + 0, lane);
        Bg2n[1] = load_bh(wsf, FR_G2N + 1, lane);

        // S1N: rows-on-M, iterate neighbors, register relu-accumulation
        {
            f32x4 acc[4];
            #pragma unroll
            for (int nt = 0; nt < 4; ++nt) acc[nt] = cinit(0.f);
            #pragma unroll 8
            for (int mm = 0; mm < 16; ++mm) {
                const float* e = xrow + 5 + 4 * mm;
                f16x8 A = make_a4(e[0], e[1], e[2], e[3]);
                #pragma unroll
                for (int nt = 0; nt < 4; ++nt) {
                    f32x4 cc = mfma1(A, Bs1n[nt], cinit(b_s1n[nt]));
                    #pragma unroll
                    for (int reg = 0; reg < 4; ++reg)
                        acc[nt][reg] += fmaxf(cc[reg], 0.f);
                }
            }
            #pragma unroll
            for (int nt = 0; nt < 4; ++nt)
                #pragma unroll
                for (int reg = 0; reg < 4; ++reg)
                    *(_Float16*)(BIGN + (q * 4 + reg) * BIG_STR + (nt * 16 + c) * 2)
                        = (_Float16)acc[nt][reg];
        }
        f16x8 Brna[4];
        #pragma unroll
        for (int nt = 0; nt < 4; ++nt) Brna[nt] = load_bh(wsf, FR_RNA + nt, lane);
        lds_order();

        // G2N -> PHN
        {
            f16x8 A0 = lds_af(BIGN, BIG_STR, 0, lane);
            f16x8 A1 = lds_af(BIGN, BIG_STR, 64, lane);
            f32x4 ca = mfma1(A0, Bg2n[0], cinit(b_g2n));
            f32x4 cb = mfma1(A1, Bg2n[1], cinit(0.f));
            #pragma unroll
            for (int reg = 0; reg < 4; ++reg)
                *(_Float16*)(PHN + (q * 4 + reg) * PHI_STR + c * 2) = (_Float16)(ca[reg] + cb[reg]);
        }
        f16x8 Brnb[2];
        Brnb[0] = load_bh(wsf, FR_RNB + 0, lane);
        Brnb[1] = load_bh(wsf, FR_RNB + 1, lane);
        lds_order();

        // RNA -> BIGN
        {
            f16x8 A = lds_af(PHN, PHI_STR, 0, lane);
            #pragma unroll
            for (int nt = 0; nt < 4; ++nt) {
                f32x4 cc = mfma1(A, Brna[nt], cinit(b_rna[nt]));
                #pragma unroll
                for (int reg = 0; reg < 4; ++reg)
                    *(_Float16*)(BIGN + (q * 4 + reg) * BIG_STR + (nt * 16 + c) * 2) = (_Float16)fmaxf(cc[reg], 0.f);
            }
        }
        lds_order();

        // RNB -> CAT cols 0..15
        {
            f16x8 A0 = lds_af(BIGN, BIG_STR, 0, lane);
            f16x8 A1 = lds_af(BIGN, BIG_STR, 64, lane);
            f32x4 ca = mfma1(A0, Brnb[0], cinit(b_rnb));
            f32x4 cb = mfma1(A1, Brnb[1], cinit(0.f));
            #pragma unroll
            for (int reg = 0; reg < 4; ++reg)
                *(_Float16*)(CAT + (q * 4 + reg) * CAT_STR + c * 2) = (_Float16)(ca[reg] + cb[reg]);
        }
    } else {
        // =================== WAVE 1: obstacle chain + barrier + g ===========
        // zero PHO junk + CAT bytes 64..127 (k=32..63 zone; g overwrites 64..71)
        for (int i = lane; i < 128; i += 64) {
            int r = i >> 3, d = i & 7;
            *(unsigned*)(PHO + r * PHI_STR + 32 + d * 4) = 0;
        }
        for (int i = lane; i < 256; i += 64) {
            int r = i >> 4, d = i & 15;
            *(unsigned*)(CAT + r * CAT_STR + 64 + d * 4) = 0;
        }
        lds_order();

        // g -> CAT k=32..35 (after zeros, same wave -> DS in-order)
        if (lane < 16) {
            const float* xr = x + (size_t)(row0 + lane) * XW;
            uint2 gv;
            gv.x = pk2(xr[1], xr[2]);
            gv.y = pk2(xr[3], xr[4]);
            *(uint2*)(CAT + lane * CAT_STR + 64) = gv;
        }

        // barrier terms: lane (row=m, quad q): nbrs 4q..4q+3, obs 2q..2q+1
        {
            float bx = 0.f, by = 0.f;
            #pragma unroll
            for (int i = 0; i < 4; ++i) {
                int n = 4 * q + i;
                float px = -xrow[5 + 4 * n], py = -xrow[6 + 4 * n];
                float nrm = fast_sqrt(px * px + py * py);
                float coef = 0.05f * fast_rcp(nrm * (nrm - 0.3f));
                bx = fmaf(coef, px, bx);
                by = fmaf(coef, py, by);
            }
            #pragma unroll
            for (int i = 0; i < 2; ++i) {
                int o = 2 * q + i;
                float px = -xrow[69 + 2 * o], py = -xrow[70 + 2 * o];
                float nrm = fast_sqrt(px * px + py * py);
                float coef = 0.05f * fast_rcp(nrm * (nrm - 0.3f));
                bx = fmaf(coef, px, bx);
                by = fmaf(coef, py, by);
            }
            bx += __shfl_xor(bx, 16); by += __shfl_xor(by, 16);
            bx += __shfl_xor(bx, 32); by += __shfl_xor(by, 32);
            if (q == 0) { float2 bb; bb.x = bx; bb.y = by; *(float2*)(BAR + m * 8) = bb; }
        }

        float b_s1o[4], b_roa[4];
        #pragma unroll
        for (int nt = 0; nt < 4; ++nt) {
            b_s1o[nt] = bp1o[nt * 16 + c];
            b_roa[nt] = br1o[nt * 16 + c];
        }
        float b_g2o = 8.f * bp2o[c];
        float b_rob = br2o[c];

        f16x8 Bs1o[4], Bg2o[2];
        #pragma unroll
        for (int nt = 0; nt < 4; ++nt) Bs1o[nt] = load_bh(wsf, FR_S1O + nt, lane);
        Bg2o[0] = load_bh(wsf, FR_G2O + 0, lane);
        Bg2o[1] = load_bh(wsf, FR_G2O + 1, lane);

        // S1O: rows-on-M, iterate obstacles
        {
            f32x4 acc[4];
            #pragma unroll
            for (int nt = 0; nt < 4; ++nt) acc[nt] = cinit(0.f);
            #pragma unroll
            for (int oo = 0; oo < 8; ++oo) {
                f16x8 A = make_a2(xrow[69 + 2 * oo], xrow[70 + 2 * oo]);
                #pragma unroll
                for (int nt = 0; nt < 4; ++nt) {
                    f32x4 cc = mfma1(A, Bs1o[nt], cinit(b_s1o[nt]));
                    #pragma unroll
                    for (int reg = 0; reg < 4; ++reg)
                        acc[nt][reg] += fmaxf(cc[reg], 0.f);
                }
            }
            #pragma unroll
            for (int nt = 0; nt < 4; ++nt)
                #pragma unroll
                for (int reg = 0; reg < 4; ++reg)
                    *(_Float16*)(BIGO + (q * 4 + reg) * BIG_STR + (nt * 16 + c) * 2)
                        = (_Float16)acc[nt][reg];
        }
        f16x8 Broa[4];
        #pragma unroll
        for (int nt = 0; nt < 4; ++nt) Broa[nt] = load_bh(wsf, FR_ROA + nt, lane);
        lds_order();

        // G2O -> PHO
        {
            f16x8 A0 = lds_af(BIGO, BIG_STR, 0, lane);
            f16x8 A1 = lds_af(BIGO, BIG_STR, 64, lane);
            f32x4 ca = mfma1(A0, Bg2o[0], cinit(b_g2o));
            f32x4 cb = mfma1(A1, Bg2o[1], cinit(0.f));
            #pragma unroll
            for (int reg = 0; reg < 4; ++reg)
                *(_Float16*)(PHO + (q * 4 + reg) * PHI_STR + c * 2) = (_Float16)(ca[reg] + cb[reg]);
        }
        f16x8 Brob[2];
        Brob[0] = load_bh(wsf, FR_ROB + 0, lane);
        Brob[1] = load_bh(wsf, FR_ROB + 1, lane);
        lds_order();

        // ROA -> BIGO
        {
            f16x8 A = lds_af(PHO, PHI_STR, 0, lane);
            #pragma unroll
            for (int nt = 0; nt < 4; ++nt) {
                f32x4 cc = mfma1(A, Broa[nt], cinit(b_roa[nt]));
                #pragma unroll
                for (int reg = 0; reg < 4; ++reg)
                    *(_Float16*)(BIGO + (q * 4 + reg) * BIG_STR + (nt * 16 + c) * 2) = (_Float16)fmaxf(cc[reg], 0.f);
            }
        }
        lds_order();

        // ROB -> CAT cols 16..31
        {
            f16x8 A0 = lds_af(BIGO, BIG_STR, 0, lane);
            f16x8 A1 = lds_af(BIGO, BIG_STR, 64, lane);
            f32x4 ca = mfma1(A0, Brob[0], cinit(b_rob));
            f32x4 cb = mfma1(A1, Brob[1], cinit(0.f));
            #pragma unroll
            for (int reg = 0; reg < 4; ++reg)
                *(_Float16*)(CAT + (q * 4 + reg) * CAT_STR + (16 + c) * 2) = (_Float16)(ca[reg] + cb[reg]);
        }
    }

    // =================== CAT handoff (cross-wave) ==========================
    __syncthreads();

    if (role == 1) {
        float b_p1[4];
        #pragma unroll
        for (int nt = 0; nt < 4; ++nt) b_p1[nt] = bpsi1[nt * 16 + c];
        float b_p2 = (c < 2) ? bpsi2[c] : 0.f;

        f16x8 Bp1a[4], Bp1b[4], Bp2[2];
        #pragma unroll
        for (int nt = 0; nt < 4; ++nt) Bp1a[nt] = load_bh(wsf, FR_PSI1 + nt, lane);
        #pragma unroll
        for (int nt = 0; nt < 4; ++nt) Bp1b[nt] = load_bh(wsf, FR_PSI1 + 4 + nt, lane);
        Bp2[0] = load_bh(wsf, FR_PSI2 + 0, lane);
        Bp2[1] = load_bh(wsf, FR_PSI2 + 1, lane);

        // PSI1 -> BIGO (reused as h3)
        {
            f16x8 A0 = lds_af(CAT, CAT_STR, 0, lane);    // k 0..31
            f16x8 A1 = lds_af(CAT, CAT_STR, 64, lane);   // k 32..63 (36.. zero)
            #pragma unroll
            for (int nt = 0; nt < 4; ++nt) {
                f32x4 ca = mfma1(A0, Bp1a[nt], cinit(b_p1[nt]));
                f32x4 cb = mfma1(A1, Bp1b[nt], cinit(0.f));
                #pragma unroll
                for (int reg = 0; reg < 4; ++reg)
                    *(_Float16*)(BIGO + (q * 4 + reg) * BIG_STR + (nt * 16 + c) * 2) = (_Float16)fmaxf(ca[reg] + cb[reg], 0.f);
            }
        }
        lds_order();

        // PSI2 -> OUT
        {
            f16x8 A0 = lds_af(BIGO, BIG_STR, 0, lane);
            f16x8 A1 = lds_af(BIGO, BIG_STR, 64, lane);
            f32x4 ca = mfma1(A0, Bp2[0], cinit(b_p2));
            f32x4 cb = mfma1(A1, Bp2[1], cinit(0.f));
            if (c < 2) {
                #pragma unroll
                for (int reg = 0; reg < 4; ++reg)
                    *(float*)(OUTA + (q * 4 + reg) * 8 + c * 4) = ca[reg] + cb[reg];
            }
        }
        lds_order();

        // epilogue
        if (lane < 16) {
            float2 a  = *(const float2*)(OUTA + lane * 8);
            float2 bb = *(const float2*)(BAR + lane * 8);
            float a0 = two_tanh(a.x) + bb.x;
            float a1 = two_tanh(a.y) + bb.y;
            float amax = fmaxf(fabsf(a0), fabsf(a1));
            float inv_alpha = fmaxf(amax * 0.5f, 1.0f);
            float rr = fast_rcp(inv_alpha);
            float2 o; o.x = a0 * rr; o.y = a1 * rr;
            *(float2*)(out + (size_t)(row0 + lane) * 2) = o;
        }
    }
}

extern "C" void kernel_launch(void* const* d_in, const int* in_sizes, int n_in,
                              void* d_out, int out_size, void* d_ws, size_t ws_size,
                              hipStream_t stream) {
    const float* x     = (const float*)d_in[0];
    const float* Wp1n  = (const float*)d_in[1];
    const float* bp1n  = (const float*)d_in[2];
    const float* Wp2n  = (const float*)d_in[3];
    const float* bp2n  = (const float*)d_in[4];
    const float* Wr1n  = (const float*)d_in[5];
    const float* br1n  = (const float*)d_in[6];
    const float* Wr2n  = (const float*)d_in[7];
    const float* br2n  = (const float*)d_in[8];
    const float* Wp1o  = (const float*)d_in[9];
    const float* bp1o  = (const float*)d_in[10];
    const float* Wp2o  = (const float*)d_in[11];
    const float* bp2o  = (const float*)d_in[12];
    const float* Wr1o  = (const float*)d_in[13];
    const float* br1o  = (const float*)d_in[14];
    const float* Wr2o  = (const float*)d_in[15];
    const float* br2o  = (const float*)d_in[16];
    const float* Wpsi1 = (const float*)d_in[17];
    const float* bpsi1 = (const float*)d_in[18];
    const float* Wpsi2 = (const float*)d_in[19];
    const float* bpsi2 = (const float*)d_in[20];
    float* out = (float*)d_out;

    int nb = in_sizes[0] / XW;               // 131072
    _Float16* wsf = (_Float16*)d_ws;         // ~34 KB frag table

    bn_prep<<<N_FRAGS, 64, 0, stream>>>(Wp1n, Wp2n, Wr1n, Wr2n,
                                        Wp1o, Wp2o, Wr1o, Wr2o,
                                        Wpsi1, Wpsi2, wsf);

    int groups = (nb + 15) / 16;             // 8192
    int blocks = (groups + 1) / 2;           // 4096 (2 groups per block)
    bn_main<<<blocks, 256, 0, stream>>>(x, wsf,
                                        bp1n, bp2n, br1n, br2n,
                                        bp1o, bp2o, br1o, br2o,
                                        bpsi1, bpsi2, out, nb);
}